// Round 10
// baseline (367.928 us; speedup 1.0000x reference)
//
#include <hip/hip_runtime.h>
#include <hip/hip_bf16.h>
#include <math.h>

#define B_ 4
#define S_ 2048
#define D_ 768
#define H_ 12
#define DH_ 64
#define F_ 3072
#define NTOK (B_*S_)   // 8192
#define BH_ (B_*H_)    // 48

typedef __hip_bfloat16 bf16;
typedef __attribute__((ext_vector_type(8))) short bf16x8;   // 8 bf16 = 4 VGPRs (MFMA A/B frag)
typedef __attribute__((ext_vector_type(4))) float f32x4;    // MFMA C/D frag
typedef __attribute__((ext_vector_type(4))) _Float16 half4;
typedef __attribute__((ext_vector_type(8))) _Float16 half8;
typedef __attribute__((ext_vector_type(2))) __fp16 fp16x2;  // cvt_pkrtz result type

// async global->LDS: 16 B/lane, lane i lands at ldsbase + i*16 (wave-uniform base)
#define GLD16(g, l) __builtin_amdgcn_global_load_lds( \
    (__attribute__((address_space(1))) void*)(uintptr_t)(g), \
    (__attribute__((address_space(3))) void*)(uintptr_t)(l), 16, 0, 0)

__device__ __forceinline__ float bs2f(short s){
  union { unsigned int u; float f; } cv; cv.u = ((unsigned int)(unsigned short)s) << 16; return cv.f;
}
__device__ __forceinline__ float b2f(bf16 v){ return __bfloat162float(v); }
__device__ __forceinline__ bf16 f2b(float v){ return __float2bfloat16(v); }
__device__ __forceinline__ short f2bb(float v){ bf16 b = f2b(v); short s; __builtin_memcpy(&s, &b, 2); return s; }

// pack 4 floats -> half4 via v_cvt_pkrtz_f16_f32 pairs
__device__ __forceinline__ half4 pk4(float p0, float p1, float p2, float p3){
  union { fp16x2 v2[2]; half4 v4; } u;
  u.v2[0] = __builtin_amdgcn_cvt_pkrtz(p0, p1);
  u.v2[1] = __builtin_amdgcn_cvt_pkrtz(p2, p3);
  return u.v4;
}

// raw workgroup barrier (no vmcnt(0) drain like __syncthreads) + compiler mem fence
__device__ __forceinline__ void wgbar(){
  __builtin_amdgcn_s_barrier();
  asm volatile("" ::: "memory");
}
// barrier that guarantees this wave's ds ops are visible (lgkmcnt only, no vmcnt drain)
__device__ __forceinline__ void wgbar_lds(){
  asm volatile("s_waitcnt lgkmcnt(0)" ::: "memory");
  __builtin_amdgcn_s_barrier();
  asm volatile("" ::: "memory");
}

// tanh-form GELU rewritten: 0.5x(1+tanh(u)) = x * rcp(1 + exp2(x*(c0 + c1*x^2)))
__device__ __forceinline__ float gelu_fast(float v){
  const float c0 = -2.302208157f;
  const float c1 = -0.102943238f;
  float w = v*v;
  float z = v * __builtin_fmaf(c1, w, c0);
  float t = __builtin_amdgcn_exp2f(z);
  return v * __builtin_amdgcn_rcpf(1.0f + t);
}

// ============ fused prep: fp32->bf16 cvt | 3 weight transposes | qkv pack ============
__global__ __launch_bounds__(256) void prep_k(
    const float4* __restrict__ x4, short4* __restrict__ xb4,
    const float* __restrict__ Wo, bf16* __restrict__ WoT,
    const float* __restrict__ W1, bf16* __restrict__ W1T,
    const float* __restrict__ W2, bf16* __restrict__ W2T,
    const float* __restrict__ Wq, const float* __restrict__ bq,
    const float* __restrict__ Wk, const float* __restrict__ bk,
    const float* __restrict__ Wv, const float* __restrict__ bv,
    bf16* __restrict__ Wt, float* __restrict__ bcat)
{
  __shared__ float t[32][33];
  int bid = blockIdx.x;
  const int tidx = threadIdx.x;

  if (bid < 6144){                       // ---- cvt ----
    const int i = bid*256 + tidx;
    float4 v = x4[i];
    short4 o;
    o.x = f2bb(v.x); o.y = f2bb(v.y); o.z = f2bb(v.z); o.w = f2bb(v.w);
    xb4[i] = o;
    return;
  }
  bid -= 6144;
  if (bid >= 576 + 2304 + 2304){         // ---- qkv pack ----
    bid -= 576 + 2304 + 2304;
    const int idx = bid*256 + tidx;
    {
      int n = idx / D_;
      int k = idx - n*D_;
      int which = n / D_;
      int cc = n - which*D_;
      int h = cc >> 6, e = cc & 63;
      const float* W = (which==0) ? Wq : ((which==1) ? Wk : Wv);
      Wt[idx] = f2b(W[((size_t)h*D_ + k)*DH_ + e]);
    }
    if (idx < 3*D_){
      int which = idx / D_;
      int cc = idx - which*D_;
      int h = cc >> 6, e = cc & 63;
      const float* bb = (which==0) ? bq : ((which==1) ? bk : bv);
      bcat[idx] = bb[h*DH_ + e];
    }
    return;
  }
  // ---- transposes: in[K][N] f32 -> out[N][K] bf16 ----
  const float* tin; bf16* tout; int K, N, tiles_x;
  if (bid < 576){ tin = Wo; tout = WoT; K = D_; N = D_; tiles_x = 24; }
  else if (bid < 576 + 2304){ bid -= 576; tin = W1; tout = W1T; K = D_; N = F_; tiles_x = 96; }
  else { bid -= 576 + 2304; tin = W2; tout = W2T; K = F_; N = D_; tiles_x = 24; }
  const int kb = (bid / tiles_x)*32, nb = (bid % tiles_x)*32;
  const int xx = tidx & 31, y = tidx >> 5;
#pragma unroll
  for (int yy = y; yy < 32; yy += 8)
    t[yy][xx] = tin[(size_t)(kb+yy)*N + nb + xx];
  __syncthreads();
#pragma unroll
  for (int yy = y; yy < 32; yy += 8)
    tout[(size_t)(nb+yy)*K + kb + xx] = f2b(t[xx][yy]);
}

// ============ MFMA GEMM 128x128, BK=32, double-buffered, 32 KB LDS -> 4 blocks/CU ============
// m97-class structure with dbuf: per K-step issue next tile's 4 GLD16, compute current
// buffer (8 frag reads + 16 MFMA/wave), single vmcnt(0)+s_barrier.  16 waves/CU resident
// (4 blocks x 4 waves) overlap the barrier drains across blocks (m114 wave-level overlap).
// 64 B row pitch: frag reads (row=i*16+l16, chunk=quad) cover all 8 16B-superbanks evenly
// -> conflict-free unpadded, staging fully coalesced, no swizzle needed.
// EPI 0: qkv scatter (q pre-scaled 1/8*log2e, V -> transposed+sigma-permuted f16)
// EPI 1: C = A@Bt^T + bias + aux (residual), bf16;  EPI 2: C = gelu(A@Bt^T + bias)
template<int EPI>
__global__ __launch_bounds__(256) void mgemm128_k(
    const bf16* __restrict__ A, const bf16* __restrict__ Bt,
    const float* __restrict__ bias, const bf16* __restrict__ aux,
    bf16* __restrict__ C, int M, int N, int K,
    bf16* __restrict__ qb, bf16* __restrict__ kbuf, _Float16* __restrict__ vt)
{
  __shared__ __align__(16) bf16 As[8192];   // [2][128][32] 16 KB
  __shared__ __align__(16) bf16 Bs[8192];   // [2][128][32] 16 KB
  const int tid  = threadIdx.x;
  const int wave = tid >> 6, lane = tid & 63;
  const int quad = lane >> 4, l16 = lane & 15;
  const int wm = (wave >> 1) * 64, wn = (wave & 1) * 64;

  const int NX = gridDim.x;
  const int f  = blockIdx.y * NX + blockIdx.x;
  const int xcd = f & 7;
  const int j   = f >> 3;
  const int bx  = j % NX;
  const int by  = (j / NX) * 8 + xcd;
  const int m0 = by * 128, n0 = bx * 128;

  // staging: wave w covers rows w*32+[0,16) and w*32+[16,32); lane -> row (lane>>2),
  // 16B chunk (lane&3).  One GLD16 per wave covers 16 rows x 64 B, coalesced source.
  const int srow = lane >> 2;           // 0..15
  const int sc   = (lane & 3) * 8;      // element offset in 32-col row
  const bf16* gA0 = A  + (size_t)(m0 + wave*32 + srow)*K + sc;
  const bf16* gA1 = gA0 + (size_t)16*K;
  const bf16* gB0 = Bt + (size_t)(n0 + wave*32 + srow)*K + sc;
  const bf16* gB1 = gB0 + (size_t)16*K;
  const uintptr_t asb = (uintptr_t)(void*)As + (size_t)wave*32*64;
  const uintptr_t bsb = (uintptr_t)(void*)Bs + (size_t)wave*32*64;

  f32x4 acc[4][4];
#pragma unroll
  for (int i=0;i<4;i++)
#pragma unroll
    for (int j2=0;j2<4;j2++) acc[i][j2] = (f32x4)0.f;

  const char* AsB = (const char*)As;
  const char* BsB = (const char*)Bs;
  const int KT = K >> 5;

  // prologue: stage tile 0 into buf0
  GLD16(gA0, asb);        GLD16(gA1, asb + 1024);
  GLD16(gB0, bsb);        GLD16(gB1, bsb + 1024);
  gA0 += 32; gA1 += 32; gB0 += 32; gB1 += 32;
  asm volatile("s_waitcnt vmcnt(0)" ::: "memory");
  wgbar();

  for (int kt = 0; kt < KT; ++kt){
    const int cur = kt & 1, nxt = cur ^ 1;
    const bool pf = (kt + 1) < KT;
    if (pf){
      GLD16(gA0, asb + nxt*8192);        GLD16(gA1, asb + nxt*8192 + 1024);
      GLD16(gB0, bsb + nxt*8192);        GLD16(gB1, bsb + nxt*8192 + 1024);
      gA0 += 32; gA1 += 32; gB0 += 32; gB1 += 32;
    }
    const char* Ac = AsB + cur*8192;
    const char* Bc = BsB + cur*8192;
    bf16x8 af[4], bfr[4];
#pragma unroll
    for (int i=0;i<4;i++)
      af[i] = *(const bf16x8*)(Ac + ((wm + i*16 + l16) << 6) + quad*16);
#pragma unroll
    for (int j2=0;j2<4;j2++)
      bfr[j2] = *(const bf16x8*)(Bc + ((wn + j2*16 + l16) << 6) + quad*16);
#pragma unroll
    for (int i=0;i<4;i++)
#pragma unroll
      for (int j2=0;j2<4;j2++)
        acc[i][j2] = __builtin_amdgcn_mfma_f32_16x16x32_bf16(af[i], bfr[j2], acc[i][j2], 0, 0, 0);
    if (pf) asm volatile("s_waitcnt vmcnt(0)" ::: "memory");
    wgbar();
  }

  // -------- epilogue --------
#pragma unroll
  for (int i=0;i<4;i++){
#pragma unroll
    for (int j2=0;j2<4;j2++){
      const int n = n0 + wn + j2*16 + l16;
      const int m_base = m0 + wm + i*16 + quad*4;
      if (EPI == 0){
        const int which = n / D_;
        const int cc = n - which*D_;
        const int h = cc >> 6, e = cc & 63;
        if (which == 2){
          const int b = m_base >> 11, s = m_base & (S_-1);
          const int sl = s & 63;
          // sigma perm: p = (s&32) | (((s>>2)&3)<<3) | (s&3) | ((s&16)>>2)
          const int perm = (sl & 32) | (((sl >> 2) & 3) << 3) | ((sl & 16) >> 2);
          half4 hv;
#pragma unroll
          for (int r=0;r<4;r++) hv[r] = (_Float16)(acc[i][j2][r] + bias[n]);
          *(half4*)(vt + ((size_t)(b*H_+h)*DH_ + e)*S_ + (s & ~63) + perm) = hv;
        } else {
          bf16* dst = (which==0) ? qb : kbuf;
          // q: fold softmax 1/sqrt(64) AND log2(e) (exp2-domain softmax) into prescale
          const float sc2 = (which==0) ? 0.18033688f : 1.0f;
#pragma unroll
          for (int r=0;r<4;r++){
            const int m = m_base + r;
            const int b = m >> 11, s = m & (S_-1);
            dst[((size_t)(b*H_+h)*S_ + s)*DH_ + e] = f2b((acc[i][j2][r] + bias[n]) * sc2);
          }
        }
      } else if (EPI == 1){
#pragma unroll
        for (int r=0;r<4;r++){
          const int m = m_base + r;
          float v = acc[i][j2][r] + bias[n] + b2f(aux[(size_t)m*N + n]);
          C[(size_t)m*N + n] = f2b(v);
        }
      } else {
#pragma unroll
        for (int r=0;r<4;r++){
          const int m = m_base + r;
          float v = acc[i][j2][r] + bias[n];
          C[(size_t)m*N + n] = f2b(gelu_fast(v));
        }
      }
    }
  }
}

// ======== MFMA flash attention: QBLK=64 wave-owns-16q, XOR-swizzled LDS, K=32 f16 PV ========
// (unchanged from round 9 — conflicts fixed, fattn now < GEMM durations)
__global__ __launch_bounds__(256, 4) void fattn_k(const bf16* __restrict__ qb,
    const bf16* __restrict__ kb, const _Float16* __restrict__ vt, bf16* __restrict__ ctx)
{
  __shared__ __align__(16) char smem[32768];
  char* kp0 = smem;             // K buf A: [64][128B] swizzled (8 KB)
  char* kp1 = smem + 8192;      // K buf B
  char* vp0 = smem + 16384;     // V buf A (f16, sigma-permuted key positions)
  char* vp1 = smem + 24576;     // V buf B

  const int bh = blockIdx.x;
  const int qt = 31 - blockIdx.y;       // heavy tiles first
  const int q0 = qt * 64;
  const int tid = threadIdx.x;
  const int wave = tid >> 6, lane = tid & 63;
  const int quad = lane >> 4, l16 = lane & 15;
  const size_t kbase = (size_t)bh * S_ * DH_;
  const int nt = qt + 1;

  // staging: thread covers row sr, 16B chunks c0, c0+1 (of 8 per row)
  const int sr = tid >> 2;              // 0..63
  const int c0 = (tid & 3) * 2;         // 0,2,4,6
  const int w0 = sr*128 + ((c0 ^ (sr & 7)) << 4);
  const int w1 = sr*128 + (((c0 + 1) ^ (sr & 7)) << 4);
  const int ge0 = c0*8, ge1 = c0*8 + 8; // global element offsets (bf16/f16)

  // frag-read swizzled chunk offsets (row & 7 == l16 & 7 for rows mf*16 + l16)
  const int sA0 = ((quad       ^ (l16 & 7)) << 4);
  const int sA1 = (((4 + quad) ^ (l16 & 7)) << 4);

  // wave owns q rows q0 + wave*16 + l16
  const int qloc = wave*16 + l16;
  const int qglob = q0 + qloc;
  bf16x8 qf[2];
#pragma unroll
  for (int h=0; h<2; h++)
    qf[h] = *(const bf16x8*)(qb + kbase + (size_t)qglob*DH_ + h*32 + quad*8);

  f32x4 o[4];                          // o[df][r] = O[dh=df*16+quad*4+r][q=own row]
#pragma unroll
  for (int df=0; df<4; df++) o[df] = (f32x4)0.f;
  float mi = -1e30f, li = 0.f;

  // ---- prologue: tile 0 -> LDS (kp0/vp0); tile 1 -> regs ----
  bf16x8 ka0, ka1; half8 va0, va1;
  {
    const bf16* ks = kb + kbase + (size_t)sr*DH_;
    ka0 = *(const bf16x8*)(ks + ge0);
    ka1 = *(const bf16x8*)(ks + ge1);
    const _Float16* vs = vt + ((size_t)bh*DH_ + sr)*S_;
    va0 = *(const half8*)(vs + ge0);
    va1 = *(const half8*)(vs + ge1);
  }
  *(bf16x8*)(kp0 + w0) = ka0;
  *(bf16x8*)(kp0 + w1) = ka1;
  *(half8*)(vp0 + w0)  = va0;
  *(half8*)(vp0 + w1)  = va1;
  if (nt > 1){
    const bf16* ks = kb + kbase + (size_t)(64 + sr)*DH_;
    ka0 = *(const bf16x8*)(ks + ge0);
    ka1 = *(const bf16x8*)(ks + ge1);
    const _Float16* vs = vt + ((size_t)bh*DH_ + sr)*S_ + 64;
    va0 = *(const half8*)(vs + ge0);
    va1 = *(const half8*)(vs + ge1);
  }
  wgbar_lds();

  for (int kt = 0; kt < nt; ++kt){
    // -------- pre-barrier: QK^T(kt), row max, V(kt)->regs, stage kt+1, load kt+2 --------
    f32x4 sc[4];
#pragma unroll
    for (int mf=0; mf<4; mf++){
      const int rb = (mf*16 + l16) * 128;
      bf16x8 a0 = *(const bf16x8*)(kp0 + rb + sA0);
      bf16x8 a1 = *(const bf16x8*)(kp0 + rb + sA1);
      f32x4 t = __builtin_amdgcn_mfma_f32_16x16x32_bf16(a0, qf[0], (f32x4)0.f, 0, 0, 0);
      sc[mf]  = __builtin_amdgcn_mfma_f32_16x16x32_bf16(a1, qf[1], t, 0, 0, 0);
    }

    if (kt == qt){
#pragma unroll
      for (int mf=0; mf<4; mf++){
        const int keyl = mf*16 + quad*4;
#pragma unroll
        for (int r=0; r<4; r++)
          if (keyl + r > qloc) sc[mf][r] = -1e30f;
      }
    }

    float mx = -1e30f;
#pragma unroll
    for (int mf=0; mf<4; mf++)
#pragma unroll
      for (int r=0; r<4; r++) mx = fmaxf(mx, sc[mf][r]);
    mx = fmaxf(mx, __shfl_xor(mx, 16));
    mx = fmaxf(mx, __shfl_xor(mx, 32));

    // V(kt): LDS -> regs (pre-barrier so vp0 can be overwritten next interval)
    half8 vva[4], vvb[4];
#pragma unroll
    for (int df=0; df<4; df++){
      const int rb = (df*16 + l16) * 128;
      vva[df] = *(const half8*)(vp0 + rb + sA0);   // positions 0..31  (chunk quad)
      vvb[df] = *(const half8*)(vp0 + rb + sA1);   // positions 32..63 (chunk 4+quad)
    }

    if (kt + 1 < nt){
      *(bf16x8*)(kp1 + w0) = ka0;
      *(bf16x8*)(kp1 + w1) = ka1;
      *(half8*)(vp1 + w0)  = va0;
      *(half8*)(vp1 + w1)  = va1;
      if (kt + 2 < nt){
        const int k0n = (kt + 2) * 64;
        const bf16* ks = kb + kbase + (size_t)(k0n + sr)*DH_;
        ka0 = *(const bf16x8*)(ks + ge0);
        ka1 = *(const bf16x8*)(ks + ge1);
        const _Float16* vs = vt + ((size_t)bh*DH_ + sr)*S_ + k0n;
        va0 = *(const half8*)(vs + ge0);
        va1 = *(const half8*)(vs + ge1);
      }
    }
    wgbar_lds();

    // -------- post-barrier (registers only): defer-max, P, PV --------
    const bool need = !__all(mx - mi <= 8.f);
    if (need){
      const float mn = fmaxf(mi, mx);
      const float a = __builtin_amdgcn_exp2f(mi - mn);
      mi = mn; li *= a;
#pragma unroll
      for (int df=0; df<4; df++)
#pragma unroll
        for (int r=0; r<4; r++) o[df][r] *= a;
    }

    half4 pfr[4];
    float rs = 0.f;
#pragma unroll
    for (int mf=0; mf<4; mf++){
      const float p0 = __builtin_amdgcn_exp2f(sc[mf][0] - mi);
      const float p1 = __builtin_amdgcn_exp2f(sc[mf][1] - mi);
      const float p2 = __builtin_amdgcn_exp2f(sc[mf][2] - mi);
      const float p3 = __builtin_amdgcn_exp2f(sc[mf][3] - mi);
      rs += (p0 + p1) + (p2 + p3);
      pfr[mf] = pk4(p0, p1, p2, p3);
    }
    rs += __shfl_xor(rs, 16);
    rs += __shfl_xor(rs, 32);
    li += rs;

    // PV: K=32 f16 MFMA; sigma perm makes B = concat of pfr pairs
    half8 p01 = __builtin_shufflevector(pfr[0], pfr[1], 0,1,2,3,4,5,6,7);
    half8 p23 = __builtin_shufflevector(pfr[2], pfr[3], 0,1,2,3,4,5,6,7);
#pragma unroll
    for (int df=0; df<4; df++){
      o[df] = __builtin_amdgcn_mfma_f32_16x16x32_f16(vva[df], p01, o[df], 0, 0, 0);
      o[df] = __builtin_amdgcn_mfma_f32_16x16x32_f16(vvb[df], p23, o[df], 0, 0, 0);
    }

    // rotate buffers (both 2-cycle)
    { char* t_ = kp0; kp0 = kp1; kp1 = t_; }
    { char* t_ = vp0; vp0 = vp1; vp1 = t_; }
  }

  // -------- epilogue: direct write, no LDS, no barriers --------
  const int b = bh / H_, h = bh - (bh / H_)*H_;
  const float inv = 1.0f / li;
  short* cdst = (short*)ctx + ((size_t)(b*S_ + qglob))*D_ + h*DH_;
#pragma unroll
  for (int df=0; df<4; df++){
    short4 pk;
    pk.x = f2bb(o[df][0] * inv);
    pk.y = f2bb(o[df][1] * inv);
    pk.z = f2bb(o[df][2] * inv);
    pk.w = f2bb(o[df][3] * inv);
    *(short4*)(cdst + df*16 + quad*4) = pk;
  }
}

// ---------------- layernorm over D=768 (192 thr, short4 loads, 16B stores) ----------------
template<typename T> __device__ __forceinline__ void st4(T* p, size_t idx, float a, float b, float c, float d);
template<> __device__ __forceinline__ void st4<float>(float* p, size_t idx, float a, float b, float c, float d){
  float4 v; v.x=a; v.y=b; v.z=c; v.w=d; *(float4*)(p+idx) = v;
}
template<> __device__ __forceinline__ void st4<bf16>(bf16* p, size_t idx, float a, float b, float c, float d){
  short4 v; v.x=f2bb(a); v.y=f2bb(b); v.z=f2bb(c); v.w=f2bb(d); *(short4*)((short*)p+idx) = v;
}

template<typename OutT>
__global__ __launch_bounds__(192) void layernorm_k(const bf16* __restrict__ X,
    const float* __restrict__ g, const float* __restrict__ bta, OutT* __restrict__ Y)
{
  const int row = blockIdx.x;
  const int tid = threadIdx.x;
  const short4 raw = *(const short4*)((const short*)X + (size_t)row*D_ + tid*4);
  const float v0 = bs2f(raw.x), v1 = bs2f(raw.y), v2 = bs2f(raw.z), v3 = bs2f(raw.w);
  float s  = v0+v1+v2+v3;
  float s2 = v0*v0+v1*v1+v2*v2+v3*v3;
#pragma unroll
  for (int o = 32; o > 0; o >>= 1){ s += __shfl_down(s, o); s2 += __shfl_down(s2, o); }
  __shared__ float rs[3], rq[3];
  const int lane = tid & 63, w = tid >> 6;
  if (lane == 0){ rs[w] = s; rq[w] = s2; }
  __syncthreads();
  s  = rs[0]+rs[1]+rs[2];
  s2 = rq[0]+rq[1]+rq[2];
  const float mean = s * (1.0f/D_);
  const float var  = s2 * (1.0f/D_) - mean*mean;
  const float inv  = rsqrtf(var + 1e-5f);
  const float4 g4 = *(const float4*)(g + tid*4);
  const float4 b4 = *(const float4*)(bta + tid*4);
  st4(Y, (size_t)row*D_ + tid*4,
      (v0-mean)*inv*g4.x + b4.x,
      (v1-mean)*inv*g4.y + b4.y,
      (v2-mean)*inv*g4.z + b4.z,
      (v3-mean)*inv*g4.w + b4.w);
}

extern "C" void kernel_launch(void* const* d_in, const int* in_sizes, int n_in,
                              void* d_out, int out_size, void* d_ws, size_t ws_size,
                              hipStream_t stream)
{
  const float* x   = (const float*)d_in[0];
  const float* Wq  = (const float*)d_in[1];
  const float* bq  = (const float*)d_in[2];
  const float* Wk  = (const float*)d_in[3];
  const float* bk  = (const float*)d_in[4];
  const float* Wv  = (const float*)d_in[5];
  const float* bv  = (const float*)d_in[6];
  const float* Wo  = (const float*)d_in[7];
  const float* bo  = (const float*)d_in[8];
  const float* W1  = (const float*)d_in[9];
  const float* b1  = (const float*)d_in[10];
  const float* W2  = (const float*)d_in[11];
  const float* b2  = (const float*)d_in[12];
  const float* g1  = (const float*)d_in[13];
  const float* be1 = (const float*)d_in[14];
  const float* g2  = (const float*)d_in[15];
  const float* be2 = (const float*)d_in[16];
  float* out = (float*)d_out;

  char* ws = (char*)d_ws;
  size_t off = 0;
  auto alloc = [&](size_t bytes)->char*{
    char* p = ws + off; off = (off + bytes + 255) & ~(size_t)255; return p;
  };
  bf16*  xb    = (bf16*) alloc((size_t)NTOK*D_*2);
  bf16*  WcatT = (bf16*) alloc((size_t)3*D_*D_*2);
  float* bcat  = (float*)alloc((size_t)3*D_*4);
  bf16*  WoT   = (bf16*) alloc((size_t)D_*D_*2);
  bf16*  W1T   = (bf16*) alloc((size_t)F_*D_*2);
  bf16*  W2T   = (bf16*) alloc((size_t)D_*F_*2);
  bf16*  r1    = (bf16*) alloc((size_t)NTOK*F_*2);     // q,k,vt then ff1
  bf16*  qb    = r1;
  bf16*  kb    = r1 + (size_t)NTOK*D_;
  _Float16* vt = (_Float16*)(r1 + (size_t)2*NTOK*D_);  // [bh*64+d][S], f16, sigma-permuted
  bf16*  ff1   = r1;
  bf16*  ctxb  = (bf16*) alloc((size_t)NTOK*D_*2);     // ctx then y2
  bf16*  y1    = (bf16*) alloc((size_t)NTOK*D_*2);
  bf16*  hb    = (bf16*) alloc((size_t)NTOK*D_*2);
  bf16*  y2    = ctxb;

  // 0) fused prep: cvt + 3 transposes + qkv pack in one dispatch
  prep_k<<<18240, 256, 0, stream>>>(
      (const float4*)x, (short4*)xb, Wo, WoT, W1, W1T, W2, W2T,
      Wq, bq, Wk, bk, Wv, bv, WcatT, bcat);

  // 1) fused QKV projection: 128x128 tiles (BK=32, 4 blocks/CU)
  mgemm128_k<0><<<dim3(3*D_/128, NTOK/128), 256, 0, stream>>>(
      xb, WcatT, bcat, nullptr, nullptr, NTOK, 3*D_, D_, qb, kb, vt);

  // 2) MFMA flash attention -> ctx [8192,768]  (QBLK=64, 4 waves, swizzled LDS)
  fattn_k<<<dim3(BH_, S_/64), 256, 0, stream>>>(qb, kb, vt, ctxb);

  // 3) out-proj + residual: y1 = ctx@Wo + bo + x
  mgemm128_k<1><<<dim3(D_/128, NTOK/128), 256, 0, stream>>>(
      ctxb, WoT, bo, xb, y1, NTOK, D_, D_, nullptr, nullptr, nullptr);

  // 4) LN1 -> h
  layernorm_k<bf16><<<NTOK, 192, 0, stream>>>(y1, g1, be1, hb);

  // 5) FF1 + fast GELU
  mgemm128_k<2><<<dim3(F_/128, NTOK/128), 256, 0, stream>>>(
      hb, W1T, b1, nullptr, ff1, NTOK, F_, D_, nullptr, nullptr, nullptr);

  // 6) FF2 + residual: y2 = ff1@W2 + b2 + h
  mgemm128_k<1><<<dim3(D_/128, NTOK/128), 256, 0, stream>>>(
      ff1, W2T, b2, hb, y2, NTOK, D_, F_, nullptr, nullptr, nullptr);

  // 7) LN2 -> out (fp32)
  layernorm_k<float><<<NTOK, 192, 0, stream>>>(y2, g2, be2, out);
}

// Round 11
// 346.104 us; speedup vs baseline: 1.0631x; 1.0631x over previous
//
#include <hip/hip_runtime.h>
#include <hip/hip_bf16.h>
#include <math.h>

#define B_ 4
#define S_ 2048
#define D_ 768
#define H_ 12
#define DH_ 64
#define F_ 3072
#define NTOK (B_*S_)   // 8192
#define BH_ (B_*H_)    // 48

typedef __hip_bfloat16 bf16;
typedef __attribute__((ext_vector_type(8))) short bf16x8;   // 8 bf16 = 4 VGPRs (MFMA A/B frag)
typedef __attribute__((ext_vector_type(4))) float f32x4;    // MFMA C/D frag
typedef __attribute__((ext_vector_type(4))) _Float16 half4;
typedef __attribute__((ext_vector_type(8))) _Float16 half8;
typedef __attribute__((ext_vector_type(2))) __fp16 fp16x2;  // cvt_pkrtz result type

// async global->LDS: 16 B/lane, lane i lands at ldsbase + i*16 (wave-uniform base)
#define GLD16(g, l) __builtin_amdgcn_global_load_lds( \
    (__attribute__((address_space(1))) void*)(uintptr_t)(g), \
    (__attribute__((address_space(3))) void*)(uintptr_t)(l), 16, 0, 0)

__device__ __forceinline__ float bs2f(short s){
  union { unsigned int u; float f; } cv; cv.u = ((unsigned int)(unsigned short)s) << 16; return cv.f;
}
__device__ __forceinline__ float b2f(bf16 v){ return __bfloat162float(v); }
__device__ __forceinline__ bf16 f2b(float v){ return __float2bfloat16(v); }
__device__ __forceinline__ short f2bb(float v){ bf16 b = f2b(v); short s; __builtin_memcpy(&s, &b, 2); return s; }

// pack 4 floats -> half4 via v_cvt_pkrtz_f16_f32 pairs
__device__ __forceinline__ half4 pk4(float p0, float p1, float p2, float p3){
  union { fp16x2 v2[2]; half4 v4; } u;
  u.v2[0] = __builtin_amdgcn_cvt_pkrtz(p0, p1);
  u.v2[1] = __builtin_amdgcn_cvt_pkrtz(p2, p3);
  return u.v4;
}

// raw workgroup barrier (no vmcnt(0) drain like __syncthreads) + compiler mem fence
__device__ __forceinline__ void wgbar(){
  __builtin_amdgcn_s_barrier();
  asm volatile("" ::: "memory");
}
// barrier that guarantees this wave's ds ops are visible (lgkmcnt only, no vmcnt drain)
__device__ __forceinline__ void wgbar_lds(){
  asm volatile("s_waitcnt lgkmcnt(0)" ::: "memory");
  __builtin_amdgcn_s_barrier();
  asm volatile("" ::: "memory");
}

// tanh-form GELU rewritten: 0.5x(1+tanh(u)) = x * rcp(1 + exp2(x*(c0 + c1*x^2)))
__device__ __forceinline__ float gelu_fast(float v){
  const float c0 = -2.302208157f;
  const float c1 = -0.102943238f;
  float w = v*v;
  float z = v * __builtin_fmaf(c1, w, c0);
  float t = __builtin_amdgcn_exp2f(z);
  return v * __builtin_amdgcn_rcpf(1.0f + t);
}

// ============ fused prep: fp32->bf16 cvt | 3 weight transposes | qkv pack ============
__global__ __launch_bounds__(256) void prep_k(
    const float4* __restrict__ x4, short4* __restrict__ xb4,
    const float* __restrict__ Wo, bf16* __restrict__ WoT,
    const float* __restrict__ W1, bf16* __restrict__ W1T,
    const float* __restrict__ W2, bf16* __restrict__ W2T,
    const float* __restrict__ Wq, const float* __restrict__ bq,
    const float* __restrict__ Wk, const float* __restrict__ bk,
    const float* __restrict__ Wv, const float* __restrict__ bv,
    bf16* __restrict__ Wt, float* __restrict__ bcat)
{
  __shared__ float t[32][33];
  int bid = blockIdx.x;
  const int tidx = threadIdx.x;

  if (bid < 6144){                       // ---- cvt ----
    const int i = bid*256 + tidx;
    float4 v = x4[i];
    short4 o;
    o.x = f2bb(v.x); o.y = f2bb(v.y); o.z = f2bb(v.z); o.w = f2bb(v.w);
    xb4[i] = o;
    return;
  }
  bid -= 6144;
  if (bid >= 576 + 2304 + 2304){         // ---- qkv pack ----
    bid -= 576 + 2304 + 2304;
    const int idx = bid*256 + tidx;
    {
      int n = idx / D_;
      int k = idx - n*D_;
      int which = n / D_;
      int cc = n - which*D_;
      int h = cc >> 6, e = cc & 63;
      const float* W = (which==0) ? Wq : ((which==1) ? Wk : Wv);
      Wt[idx] = f2b(W[((size_t)h*D_ + k)*DH_ + e]);
    }
    if (idx < 3*D_){
      int which = idx / D_;
      int cc = idx - which*D_;
      int h = cc >> 6, e = cc & 63;
      const float* bb = (which==0) ? bq : ((which==1) ? bk : bv);
      bcat[idx] = bb[h*DH_ + e];
    }
    return;
  }
  // ---- transposes: in[K][N] f32 -> out[N][K] bf16 ----
  const float* tin; bf16* tout; int K, N, tiles_x;
  if (bid < 576){ tin = Wo; tout = WoT; K = D_; N = D_; tiles_x = 24; }
  else if (bid < 576 + 2304){ bid -= 576; tin = W1; tout = W1T; K = D_; N = F_; tiles_x = 96; }
  else { bid -= 576 + 2304; tin = W2; tout = W2T; K = F_; N = D_; tiles_x = 24; }
  const int kb = (bid / tiles_x)*32, nb = (bid % tiles_x)*32;
  const int xx = tidx & 31, y = tidx >> 5;
#pragma unroll
  for (int yy = y; yy < 32; yy += 8)
    t[yy][xx] = tin[(size_t)(kb+yy)*N + nb + xx];
  __syncthreads();
#pragma unroll
  for (int yy = y; yy < 32; yy += 8)
    tout[(size_t)(nb+yy)*K + kb + xx] = f2b(t[xx][yy]);
}

// ============ MFMA GEMM 128x128, BK=64, double-buffered 2-phase (round-9 proven) ============
// 64 KB LDS -> 2 blocks/CU.  Swizzle: slot c of row r holds global chunk c ^ (r&7);
// measured 0 bank conflicts.  Used for QKV (EPI 0) and FF1 (EPI 2).
// EPI 0: qkv scatter (q pre-scaled 1/8*log2e, V -> transposed+sigma-permuted f16)
//   V perm: key s stored at position p = (s&32) | (((s>>2)&3)<<3) | (s&3) | ((s&16)>>2)
// EPI 1: C = A@Bt^T + bias + aux (residual);  EPI 2: C = gelu(A@Bt^T + bias)
template<int EPI>
__global__ __launch_bounds__(256) void mgemm128_k(
    const bf16* __restrict__ A, const bf16* __restrict__ Bt,
    const float* __restrict__ bias, const bf16* __restrict__ aux,
    bf16* __restrict__ C, int M, int N, int K,
    bf16* __restrict__ qb, bf16* __restrict__ kbuf, _Float16* __restrict__ vt)
{
  __shared__ __align__(16) bf16 As[16384];   // [2][128][64] 32 KB
  __shared__ __align__(16) bf16 Bs[16384];   // [2][128][64] 32 KB
  const int tid  = threadIdx.x;
  const int wave = tid >> 6, lane = tid & 63;
  const int quad = lane >> 4, l16 = lane & 15;
  const int wm = (wave >> 1) * 64, wn = (wave & 1) * 64;

  const int NX = gridDim.x;
  const int f  = blockIdx.y * NX + blockIdx.x;
  const int xcd = f & 7;
  const int j   = f >> 3;
  const int bx  = j % NX;
  const int by  = (j / NX) * 8 + xcd;
  const int m0 = by * 128, n0 = bx * 128;

  const int srow8 = lane >> 3;                       // 0..7
  const int g     = (lane & 7) ^ srow8;              // global 16B-chunk within the row
  const bf16* gA = A  + (size_t)(m0 + wave*32 + srow8)*K + g*8;
  const bf16* gB = Bt + (size_t)(n0 + wave*32 + srow8)*K + g*8;
  const uintptr_t asb = (uintptr_t)(void*)As + (size_t)wave*32*128;
  const uintptr_t bsb = (uintptr_t)(void*)Bs + (size_t)wave*32*128;

  f32x4 acc[4][4];
#pragma unroll
  for (int i=0;i<4;i++)
#pragma unroll
    for (int j2=0;j2<4;j2++) acc[i][j2] = (f32x4)0.f;

  const char* AsB = (const char*)As;
  const char* BsB = (const char*)Bs;
  const int KT = K >> 6;

  // prologue: stage tile 0 into buf0
#pragma unroll
  for (int t=0;t<4;t++){
    GLD16(gA + (size_t)t*8*K, asb + t*1024);
    GLD16(gB + (size_t)t*8*K, bsb + t*1024);
  }
  gA += 64; gB += 64;
  asm volatile("s_waitcnt vmcnt(0)" ::: "memory");
  wgbar();

  for (int kt = 0; kt < KT; ++kt){
    const int cur = kt & 1, nxt = cur ^ 1;
    const bool pf = (kt + 1) < KT;
    if (pf){
      const uintptr_t ao = asb + (size_t)nxt*16384;
      const uintptr_t bo = bsb + (size_t)nxt*16384;
#pragma unroll
      for (int t=0;t<4;t++){
        GLD16(gA + (size_t)t*8*K, ao + t*1024);
        GLD16(gB + (size_t)t*8*K, bo + t*1024);
      }
      gA += 64; gB += 64;
    }
    const char* Ac = AsB + (size_t)cur*16384;
    const char* Bc = BsB + (size_t)cur*16384;
#pragma unroll
    for (int kq = 0; kq < 2; kq++){
      const int cbase = kq*4 + quad;
      bf16x8 af[4], bfr[4];
#pragma unroll
      for (int i=0;i<4;i++){
        const int m = wm + i*16 + l16;
        af[i] = *(const bf16x8*)(Ac + (m << 7) + ((cbase ^ (m & 7)) << 4));
      }
#pragma unroll
      for (int j2=0;j2<4;j2++){
        const int n = wn + j2*16 + l16;
        bfr[j2] = *(const bf16x8*)(Bc + (n << 7) + ((cbase ^ (n & 7)) << 4));
      }
#pragma unroll
      for (int i=0;i<4;i++)
#pragma unroll
        for (int j2=0;j2<4;j2++)
          acc[i][j2] = __builtin_amdgcn_mfma_f32_16x16x32_bf16(af[i], bfr[j2], acc[i][j2], 0, 0, 0);
    }
    if (pf) asm volatile("s_waitcnt vmcnt(0)" ::: "memory");
    wgbar();
  }

  // -------- epilogue --------
#pragma unroll
  for (int i=0;i<4;i++){
#pragma unroll
    for (int j2=0;j2<4;j2++){
      const int n = n0 + wn + j2*16 + l16;
      const int m_base = m0 + wm + i*16 + quad*4;
      if (EPI == 0){
        const int which = n / D_;
        const int cc = n - which*D_;
        const int h = cc >> 6, e = cc & 63;
        if (which == 2){
          const int b = m_base >> 11, s = m_base & (S_-1);
          const int sl = s & 63;
          // sigma perm: p = (s&32) | (((s>>2)&3)<<3) | (s&3) | ((s&16)>>2)
          const int perm = (sl & 32) | (((sl >> 2) & 3) << 3) | ((sl & 16) >> 2);
          half4 hv;
#pragma unroll
          for (int r=0;r<4;r++) hv[r] = (_Float16)(acc[i][j2][r] + bias[n]);
          *(half4*)(vt + ((size_t)(b*H_+h)*DH_ + e)*S_ + (s & ~63) + perm) = hv;
        } else {
          bf16* dst = (which==0) ? qb : kbuf;
          // q: fold softmax 1/sqrt(64) AND log2(e) (exp2-domain softmax) into prescale
          const float sc2 = (which==0) ? 0.18033688f : 1.0f;
#pragma unroll
          for (int r=0;r<4;r++){
            const int m = m_base + r;
            const int b = m >> 11, s = m & (S_-1);
            dst[((size_t)(b*H_+h)*S_ + s)*DH_ + e] = f2b((acc[i][j2][r] + bias[n]) * sc2);
          }
        }
      } else if (EPI == 1){
#pragma unroll
        for (int r=0;r<4;r++){
          const int m = m_base + r;
          float v = acc[i][j2][r] + bias[n] + b2f(aux[(size_t)m*N + n]);
          C[(size_t)m*N + n] = f2b(v);
        }
      } else {
#pragma unroll
        for (int r=0;r<4;r++){
          const int m = m_base + r;
          float v = acc[i][j2][r] + bias[n];
          C[(size_t)m*N + n] = f2b(gelu_fast(v));
        }
      }
    }
  }
}

// ============ MFMA GEMM 128x64, BK=64, dbuf — for N=768 GEMMs (proj, FF2) ============
// LDS 48 KB -> 3 blocks/CU (12 waves, m114 cross-block overlap); grid 12x64 = 768 blocks
// = EXACTLY 3/CU x 256 CU, perfect packing (128x128 left 25% of slots idle at N=768).
// 4 waves 2Mx2N, per-wave 64x32 out, 16 MFMA/K-step.  Same proven 128 B-pitch XOR swizzle.
// C = A@Bt^T + bias + aux (residual), bf16 out.
__global__ __launch_bounds__(256) void mgemmN64_k(
    const bf16* __restrict__ A, const bf16* __restrict__ Bt,
    const float* __restrict__ bias, const bf16* __restrict__ aux,
    bf16* __restrict__ C, int M, int N, int K)
{
  __shared__ __align__(16) bf16 As[16384];   // [2][128][64] 32 KB
  __shared__ __align__(16) bf16 Bs[8192];    // [2][64][64]  16 KB
  const int tid  = threadIdx.x;
  const int wave = tid >> 6, lane = tid & 63;
  const int quad = lane >> 4, l16 = lane & 15;
  const int wm = (wave >> 1) * 64, wn = (wave & 1) * 32;

  const int NX = gridDim.x;
  const int f  = blockIdx.y * NX + blockIdx.x;
  const int xcd = f & 7;
  const int j   = f >> 3;
  const int bx  = j % NX;
  const int by  = (j / NX) * 8 + xcd;
  const int m0 = by * 128, n0 = bx * 64;

  const int srow8 = lane >> 3;                       // 0..7
  const int g     = (lane & 7) ^ srow8;              // global 16B-chunk within the row
  // A: wave stages rows wave*32 + t*8 + srow8 (t=0..3); B: rows wave*16 + t*8 (t=0..1)
  const bf16* gA = A  + (size_t)(m0 + wave*32 + srow8)*K + g*8;
  const bf16* gB = Bt + (size_t)(n0 + wave*16 + srow8)*K + g*8;
  const uintptr_t asb = (uintptr_t)(void*)As + (size_t)wave*32*128;
  const uintptr_t bsb = (uintptr_t)(void*)Bs + (size_t)wave*16*128;

  f32x4 acc[4][2];
#pragma unroll
  for (int i=0;i<4;i++)
#pragma unroll
    for (int j2=0;j2<2;j2++) acc[i][j2] = (f32x4)0.f;

  const char* AsB = (const char*)As;
  const char* BsB = (const char*)Bs;
  const int KT = K >> 6;

  // prologue: stage tile 0 into buf0
#pragma unroll
  for (int t=0;t<4;t++) GLD16(gA + (size_t)t*8*K, asb + t*1024);
#pragma unroll
  for (int t=0;t<2;t++) GLD16(gB + (size_t)t*8*K, bsb + t*1024);
  gA += 64; gB += 64;
  asm volatile("s_waitcnt vmcnt(0)" ::: "memory");
  wgbar();

  for (int kt = 0; kt < KT; ++kt){
    const int cur = kt & 1, nxt = cur ^ 1;
    const bool pf = (kt + 1) < KT;
    if (pf){
      const uintptr_t ao = asb + (size_t)nxt*16384;
      const uintptr_t bo = bsb + (size_t)nxt*8192;
#pragma unroll
      for (int t=0;t<4;t++) GLD16(gA + (size_t)t*8*K, ao + t*1024);
#pragma unroll
      for (int t=0;t<2;t++) GLD16(gB + (size_t)t*8*K, bo + t*1024);
      gA += 64; gB += 64;
    }
    const char* Ac = AsB + (size_t)cur*16384;
    const char* Bc = BsB + (size_t)cur*8192;
#pragma unroll
    for (int kq = 0; kq < 2; kq++){
      const int cbase = kq*4 + quad;
      bf16x8 af[4], bfr[2];
#pragma unroll
      for (int i=0;i<4;i++){
        const int m = wm + i*16 + l16;
        af[i] = *(const bf16x8*)(Ac + (m << 7) + ((cbase ^ (m & 7)) << 4));
      }
#pragma unroll
      for (int j2=0;j2<2;j2++){
        const int n = wn + j2*16 + l16;
        bfr[j2] = *(const bf16x8*)(Bc + (n << 7) + ((cbase ^ (n & 7)) << 4));
      }
#pragma unroll
      for (int i=0;i<4;i++)
#pragma unroll
        for (int j2=0;j2<2;j2++)
          acc[i][j2] = __builtin_amdgcn_mfma_f32_16x16x32_bf16(af[i], bfr[j2], acc[i][j2], 0, 0, 0);
    }
    if (pf) asm volatile("s_waitcnt vmcnt(0)" ::: "memory");
    wgbar();
  }

#pragma unroll
  for (int i=0;i<4;i++){
#pragma unroll
    for (int j2=0;j2<2;j2++){
      const int n = n0 + wn + j2*16 + l16;
      const int m_base = m0 + wm + i*16 + quad*4;
#pragma unroll
      for (int r=0;r<4;r++){
        const int m = m_base + r;
        float v = acc[i][j2][r] + bias[n] + b2f(aux[(size_t)m*N + n]);
        C[(size_t)m*N + n] = f2b(v);
      }
    }
  }
}

// ======== MFMA flash attention: QBLK=64 wave-owns-16q, XOR-swizzled LDS, K=32 f16 PV ========
// (unchanged from round 9 — conflicts fixed, fattn < GEMM durations)
__global__ __launch_bounds__(256, 4) void fattn_k(const bf16* __restrict__ qb,
    const bf16* __restrict__ kb, const _Float16* __restrict__ vt, bf16* __restrict__ ctx)
{
  __shared__ __align__(16) char smem[32768];
  char* kp0 = smem;             // K buf A: [64][128B] swizzled (8 KB)
  char* kp1 = smem + 8192;      // K buf B
  char* vp0 = smem + 16384;     // V buf A (f16, sigma-permuted key positions)
  char* vp1 = smem + 24576;     // V buf B

  const int bh = blockIdx.x;
  const int qt = 31 - blockIdx.y;       // heavy tiles first
  const int q0 = qt * 64;
  const int tid = threadIdx.x;
  const int wave = tid >> 6, lane = tid & 63;
  const int quad = lane >> 4, l16 = lane & 15;
  const size_t kbase = (size_t)bh * S_ * DH_;
  const int nt = qt + 1;

  // staging: thread covers row sr, 16B chunks c0, c0+1 (of 8 per row)
  const int sr = tid >> 2;              // 0..63
  const int c0 = (tid & 3) * 2;         // 0,2,4,6
  const int w0 = sr*128 + ((c0 ^ (sr & 7)) << 4);
  const int w1 = sr*128 + (((c0 + 1) ^ (sr & 7)) << 4);
  const int ge0 = c0*8, ge1 = c0*8 + 8; // global element offsets (bf16/f16)

  // frag-read swizzled chunk offsets (row & 7 == l16 & 7 for rows mf*16 + l16)
  const int sA0 = ((quad       ^ (l16 & 7)) << 4);
  const int sA1 = (((4 + quad) ^ (l16 & 7)) << 4);

  // wave owns q rows q0 + wave*16 + l16
  const int qloc = wave*16 + l16;
  const int qglob = q0 + qloc;
  bf16x8 qf[2];
#pragma unroll
  for (int h=0; h<2; h++)
    qf[h] = *(const bf16x8*)(qb + kbase + (size_t)qglob*DH_ + h*32 + quad*8);

  f32x4 o[4];                          // o[df][r] = O[dh=df*16+quad*4+r][q=own row]
#pragma unroll
  for (int df=0; df<4; df++) o[df] = (f32x4)0.f;
  float mi = -1e30f, li = 0.f;

  // ---- prologue: tile 0 -> LDS (kp0/vp0); tile 1 -> regs ----
  bf16x8 ka0, ka1; half8 va0, va1;
  {
    const bf16* ks = kb + kbase + (size_t)sr*DH_;
    ka0 = *(const bf16x8*)(ks + ge0);
    ka1 = *(const bf16x8*)(ks + ge1);
    const _Float16* vs = vt + ((size_t)bh*DH_ + sr)*S_;
    va0 = *(const half8*)(vs + ge0);
    va1 = *(const half8*)(vs + ge1);
  }
  *(bf16x8*)(kp0 + w0) = ka0;
  *(bf16x8*)(kp0 + w1) = ka1;
  *(half8*)(vp0 + w0)  = va0;
  *(half8*)(vp0 + w1)  = va1;
  if (nt > 1){
    const bf16* ks = kb + kbase + (size_t)(64 + sr)*DH_;
    ka0 = *(const bf16x8*)(ks + ge0);
    ka1 = *(const bf16x8*)(ks + ge1);
    const _Float16* vs = vt + ((size_t)bh*DH_ + sr)*S_ + 64;
    va0 = *(const half8*)(vs + ge0);
    va1 = *(const half8*)(vs + ge1);
  }
  wgbar_lds();

  for (int kt = 0; kt < nt; ++kt){
    // -------- pre-barrier: QK^T(kt), row max, V(kt)->regs, stage kt+1, load kt+2 --------
    f32x4 sc[4];
#pragma unroll
    for (int mf=0; mf<4; mf++){
      const int rb = (mf*16 + l16) * 128;
      bf16x8 a0 = *(const bf16x8*)(kp0 + rb + sA0);
      bf16x8 a1 = *(const bf16x8*)(kp0 + rb + sA1);
      f32x4 t = __builtin_amdgcn_mfma_f32_16x16x32_bf16(a0, qf[0], (f32x4)0.f, 0, 0, 0);
      sc[mf]  = __builtin_amdgcn_mfma_f32_16x16x32_bf16(a1, qf[1], t, 0, 0, 0);
    }

    if (kt == qt){
#pragma unroll
      for (int mf=0; mf<4; mf++){
        const int keyl = mf*16 + quad*4;
#pragma unroll
        for (int r=0; r<4; r++)
          if (keyl + r > qloc) sc[mf][r] = -1e30f;
      }
    }

    float mx = -1e30f;
#pragma unroll
    for (int mf=0; mf<4; mf++)
#pragma unroll
      for (int r=0; r<4; r++) mx = fmaxf(mx, sc[mf][r]);
    mx = fmaxf(mx, __shfl_xor(mx, 16));
    mx = fmaxf(mx, __shfl_xor(mx, 32));

    // V(kt): LDS -> regs (pre-barrier so vp0 can be overwritten next interval)
    half8 vva[4], vvb[4];
#pragma unroll
    for (int df=0; df<4; df++){
      const int rb = (df*16 + l16) * 128;
      vva[df] = *(const half8*)(vp0 + rb + sA0);   // positions 0..31  (chunk quad)
      vvb[df] = *(const half8*)(vp0 + rb + sA1);   // positions 32..63 (chunk 4+quad)
    }

    if (kt + 1 < nt){
      *(bf16x8*)(kp1 + w0) = ka0;
      *(bf16x8*)(kp1 + w1) = ka1;
      *(half8*)(vp1 + w0)  = va0;
      *(half8*)(vp1 + w1)  = va1;
      if (kt + 2 < nt){
        const int k0n = (kt + 2) * 64;
        const bf16* ks = kb + kbase + (size_t)(k0n + sr)*DH_;
        ka0 = *(const bf16x8*)(ks + ge0);
        ka1 = *(const bf16x8*)(ks + ge1);
        const _Float16* vs = vt + ((size_t)bh*DH_ + sr)*S_ + k0n;
        va0 = *(const half8*)(vs + ge0);
        va1 = *(const half8*)(vs + ge1);
      }
    }
    wgbar_lds();

    // -------- post-barrier (registers only): defer-max, P, PV --------
    const bool need = !__all(mx - mi <= 8.f);
    if (need){
      const float mn = fmaxf(mi, mx);
      const float a = __builtin_amdgcn_exp2f(mi - mn);
      mi = mn; li *= a;
#pragma unroll
      for (int df=0; df<4; df++)
#pragma unroll
        for (int r=0; r<4; r++) o[df][r] *= a;
    }

    half4 pfr[4];
    float rs = 0.f;
#pragma unroll
    for (int mf=0; mf<4; mf++){
      const float p0 = __builtin_amdgcn_exp2f(sc[mf][0] - mi);
      const float p1 = __builtin_amdgcn_exp2f(sc[mf][1] - mi);
      const float p2 = __builtin_amdgcn_exp2f(sc[mf][2] - mi);
      const float p3 = __builtin_amdgcn_exp2f(sc[mf][3] - mi);
      rs += (p0 + p1) + (p2 + p3);
      pfr[mf] = pk4(p0, p1, p2, p3);
    }
    rs += __shfl_xor(rs, 16);
    rs += __shfl_xor(rs, 32);
    li += rs;

    // PV: K=32 f16 MFMA; sigma perm makes B = concat of pfr pairs
    half8 p01 = __builtin_shufflevector(pfr[0], pfr[1], 0,1,2,3,4,5,6,7);
    half8 p23 = __builtin_shufflevector(pfr[2], pfr[3], 0,1,2,3,4,5,6,7);
#pragma unroll
    for (int df=0; df<4; df++){
      o[df] = __builtin_amdgcn_mfma_f32_16x16x32_f16(vva[df], p01, o[df], 0, 0, 0);
      o[df] = __builtin_amdgcn_mfma_f32_16x16x32_f16(vvb[df], p23, o[df], 0, 0, 0);
    }

    // rotate buffers (both 2-cycle)
    { char* t_ = kp0; kp0 = kp1; kp1 = t_; }
    { char* t_ = vp0; vp0 = vp1; vp1 = t_; }
  }

  // -------- epilogue: direct write, no LDS, no barriers --------
  const int b = bh / H_, h = bh - (bh / H_)*H_;
  const float inv = 1.0f / li;
  short* cdst = (short*)ctx + ((size_t)(b*S_ + qglob))*D_ + h*DH_;
#pragma unroll
  for (int df=0; df<4; df++){
    short4 pk;
    pk.x = f2bb(o[df][0] * inv);
    pk.y = f2bb(o[df][1] * inv);
    pk.z = f2bb(o[df][2] * inv);
    pk.w = f2bb(o[df][3] * inv);
    *(short4*)(cdst + df*16 + quad*4) = pk;
  }
}

// ---------------- layernorm over D=768 (192 thr, short4 loads, 16B stores) ----------------
template<typename T> __device__ __forceinline__ void st4(T* p, size_t idx, float a, float b, float c, float d);
template<> __device__ __forceinline__ void st4<float>(float* p, size_t idx, float a, float b, float c, float d){
  float4 v; v.x=a; v.y=b; v.z=c; v.w=d; *(float4*)(p+idx) = v;
}
template<> __device__ __forceinline__ void st4<bf16>(bf16* p, size_t idx, float a, float b, float c, float d){
  short4 v; v.x=f2bb(a); v.y=f2bb(b); v.z=f2bb(c); v.w=f2bb(d); *(short4*)((short*)p+idx) = v;
}

template<typename OutT>
__global__ __launch_bounds__(192) void layernorm_k(const bf16* __restrict__ X,
    const float* __restrict__ g, const float* __restrict__ bta, OutT* __restrict__ Y)
{
  const int row = blockIdx.x;
  const int tid = threadIdx.x;
  const short4 raw = *(const short4*)((const short*)X + (size_t)row*D_ + tid*4);
  const float v0 = bs2f(raw.x), v1 = bs2f(raw.y), v2 = bs2f(raw.z), v3 = bs2f(raw.w);
  float s  = v0+v1+v2+v3;
  float s2 = v0*v0+v1*v1+v2*v2+v3*v3;
#pragma unroll
  for (int o = 32; o > 0; o >>= 1){ s += __shfl_down(s, o); s2 += __shfl_down(s2, o); }
  __shared__ float rs[3], rq[3];
  const int lane = tid & 63, w = tid >> 6;
  if (lane == 0){ rs[w] = s; rq[w] = s2; }
  __syncthreads();
  s  = rs[0]+rs[1]+rs[2];
  s2 = rq[0]+rq[1]+rq[2];
  const float mean = s * (1.0f/D_);
  const float var  = s2 * (1.0f/D_) - mean*mean;
  const float inv  = rsqrtf(var + 1e-5f);
  const float4 g4 = *(const float4*)(g + tid*4);
  const float4 b4 = *(const float4*)(bta + tid*4);
  st4(Y, (size_t)row*D_ + tid*4,
      (v0-mean)*inv*g4.x + b4.x,
      (v1-mean)*inv*g4.y + b4.y,
      (v2-mean)*inv*g4.z + b4.z,
      (v3-mean)*inv*g4.w + b4.w);
}

extern "C" void kernel_launch(void* const* d_in, const int* in_sizes, int n_in,
                              void* d_out, int out_size, void* d_ws, size_t ws_size,
                              hipStream_t stream)
{
  const float* x   = (const float*)d_in[0];
  const float* Wq  = (const float*)d_in[1];
  const float* bq  = (const float*)d_in[2];
  const float* Wk  = (const float*)d_in[3];
  const float* bk  = (const float*)d_in[4];
  const float* Wv  = (const float*)d_in[5];
  const float* bv  = (const float*)d_in[6];
  const float* Wo  = (const float*)d_in[7];
  const float* bo  = (const float*)d_in[8];
  const float* W1  = (const float*)d_in[9];
  const float* b1  = (const float*)d_in[10];
  const float* W2  = (const float*)d_in[11];
  const float* b2  = (const float*)d_in[12];
  const float* g1  = (const float*)d_in[13];
  const float* be1 = (const float*)d_in[14];
  const float* g2  = (const float*)d_in[15];
  const float* be2 = (const float*)d_in[16];
  float* out = (float*)d_out;

  char* ws = (char*)d_ws;
  size_t off = 0;
  auto alloc = [&](size_t bytes)->char*{
    char* p = ws + off; off = (off + bytes + 255) & ~(size_t)255; return p;
  };
  bf16*  xb    = (bf16*) alloc((size_t)NTOK*D_*2);
  bf16*  WcatT = (bf16*) alloc((size_t)3*D_*D_*2);
  float* bcat  = (float*)alloc((size_t)3*D_*4);
  bf16*  WoT   = (bf16*) alloc((size_t)D_*D_*2);
  bf16*  W1T   = (bf16*) alloc((size_t)F_*D_*2);
  bf16*  W2T   = (bf16*) alloc((size_t)D_*F_*2);
  bf16*  r1    = (bf16*) alloc((size_t)NTOK*F_*2);     // q,k,vt then ff1
  bf16*  qb    = r1;
  bf16*  kb    = r1 + (size_t)NTOK*D_;
  _Float16* vt = (_Float16*)(r1 + (size_t)2*NTOK*D_);  // [bh*64+d][S], f16, sigma-permuted
  bf16*  ff1   = r1;
  bf16*  ctxb  = (bf16*) alloc((size_t)NTOK*D_*2);     // ctx then y2
  bf16*  y1    = (bf16*) alloc((size_t)NTOK*D_*2);
  bf16*  hb    = (bf16*) alloc((size_t)NTOK*D_*2);
  bf16*  y2    = ctxb;

  // 0) fused prep: cvt + 3 transposes + qkv pack in one dispatch
  prep_k<<<18240, 256, 0, stream>>>(
      (const float4*)x, (short4*)xb, Wo, WoT, W1, W1T, W2, W2T,
      Wq, bq, Wk, bk, Wv, bv, WcatT, bcat);

  // 1) fused QKV projection: 128x128 tiles (BK=64 dbuf, round-9 proven)
  mgemm128_k<0><<<dim3(3*D_/128, NTOK/128), 256, 0, stream>>>(
      xb, WcatT, bcat, nullptr, nullptr, NTOK, 3*D_, D_, qb, kb, vt);

  // 2) MFMA flash attention -> ctx [8192,768]  (QBLK=64, 4 waves, swizzled LDS)
  fattn_k<<<dim3(BH_, S_/64), 256, 0, stream>>>(qb, kb, vt, ctxb);

  // 3) out-proj + residual: y1 = ctx@Wo + bo + x   (128x64 tiles, 768 blocks = 3/CU exact)
  mgemmN64_k<<<dim3(D_/64, NTOK/128), 256, 0, stream>>>(
      ctxb, WoT, bo, xb, y1, NTOK, D_, D_);

  // 4) LN1 -> h
  layernorm_k<bf16><<<NTOK, 192, 0, stream>>>(y1, g1, be1, hb);

  // 5) FF1 + fast GELU (128x128 tiles, 1536 blocks = 3 perfect rounds)
  mgemm128_k<2><<<dim3(F_/128, NTOK/128), 256, 0, stream>>>(
      hb, W1T, b1, nullptr, ff1, NTOK, F_, D_, nullptr, nullptr, nullptr);

  // 6) FF2 + residual: y2 = ff1@W2 + b2 + h   (128x64 tiles, 768 blocks = 3/CU exact)
  mgemmN64_k<<<dim3(D_/64, NTOK/128), 256, 0, stream>>>(
      ff1, W2T, b2, hb, y2, NTOK, D_, F_);

  // 7) LN2 -> out (fp32)
  layernorm_k<float><<<NTOK, 192, 0, stream>>>(y2, g2, be2, out);
}